// Round 3
// baseline (1033.779 us; speedup 1.0000x reference)
//
#include <hip/hip_runtime.h>
#include <hip/hip_bf16.h>

#define N_NODES 20000
#define N_EDGES 320000

typedef __attribute__((ext_vector_type(8))) short short8;
typedef __attribute__((ext_vector_type(4))) float f32x4;

static __device__ __forceinline__ unsigned short f2bf(float f) {
  __hip_bfloat16 h = __float2bfloat16(f);
  union { __hip_bfloat16 h; unsigned short u; } cv; cv.h = h; return cv.u;
}

static __device__ __forceinline__ unsigned int pk2(float a, float b) {
  return (unsigned int)f2bf(a) | ((unsigned int)f2bf(b) << 16);
}

static __device__ __forceinline__ float gelu_exact(float v) {
  return 0.5f * v * (1.0f + erff(v * 0.70710678118654752f));
}

// XOR swizzle for bf16 tiles with 512B/1024B row stride (16B granule spread)
#define SWZ(row, byteoff) ((byteoff) ^ (((row) & 7) << 4))
// fp32 accumulator tile (row stride 1024B): same idea
#define A2OFF(row, colbyte) ((((row) * 1024) + (colbyte)) ^ (((row) & 7) << 4))
// fp32 U tile swizzle keyed off address bits
#define SWZU(b) ((b) ^ ((((b) >> 8) & 7) << 4))

// ---------------------------------------------------------------- zero counts
__global__ void zero_cnt_kernel(int* __restrict__ cnt) {
  int idx = blockIdx.x * blockDim.x + threadIdx.x;
  if (idx < N_NODES) cnt[idx] = 0;
}

// ---------------------------------------------------------------- weight pack
// Pack W[K][Nc] (row-major f32) into bf16 MFMA-B-fragment order:
// P[(cf*(K/32)+t)*512 + l*8 + i] = W[t*32 + (l>>4)*8 + i][cf*16 + (l&15)]
__global__ void pack_kernel(const float* __restrict__ W1m, const float* __restrict__ W2m,
                            const float* __restrict__ W1u, const float* __restrict__ W2u,
                            unsigned short* __restrict__ P1m, unsigned short* __restrict__ P2m,
                            unsigned short* __restrict__ P1u, unsigned short* __restrict__ P2u) {
  int idx = blockIdx.x * blockDim.x + threadIdx.x;
  const float* W; unsigned short* P; int K, Nc, local;
  if (idx < 65536)        { W = W1m; P = P1m; K = 256; Nc = 256; local = idx; }
  else if (idx < 131072)  { W = W2m; P = P2m; K = 256; Nc = 256; local = idx - 65536; }
  else if (idx < 262144)  { W = W1u; P = P1u; K = 256; Nc = 512; local = idx - 131072; }
  else                    { W = W2u; P = P2u; K = 512; Nc = 256; local = idx - 262144; }
  int frag = local >> 9, wi = local & 511;
  int l = wi >> 3, i = wi & 7;
  int kf = K >> 5;
  int cf = frag / kf, t = frag % kf;
  int k = t * 32 + (l >> 4) * 8 + i;
  int n = cf * 16 + (l & 15);
  P[local] = f2bf(W[(size_t)k * Nc + n]);
}

// ---------------------------------------------------------------- histogram
__global__ void hist_kernel(const int* __restrict__ dst, int* __restrict__ cnt) {
  int e = blockIdx.x * blockDim.x + threadIdx.x;
  atomicAdd(&cnt[dst[e]], 1);
}

// ---------------------------------------------------------------- prefix scan (1 block, 1024 thr)
__global__ __launch_bounds__(1024) void scan_kernel(const int* __restrict__ cnt,
                                                    int* __restrict__ rptr,
                                                    int* __restrict__ cur) {
  __shared__ int sums[1024];
  const int t = threadIdx.x;
  const int base = t * 20;
  int local[20];
  int s = 0;
#pragma unroll
  for (int i = 0; i < 20; ++i) {
    int idx = base + i;
    int v = (idx < N_NODES) ? cnt[idx] : 0;
    local[i] = s;
    s += v;
  }
  int v = s;
  sums[t] = v;
  for (int off = 1; off < 1024; off <<= 1) {
    __syncthreads();
    int o = (t >= off) ? sums[t - off] : 0;
    __syncthreads();
    v += o;
    sums[t] = v;
  }
  int excl = v - s;
#pragma unroll
  for (int i = 0; i < 20; ++i) {
    int idx = base + i;
    if (idx < N_NODES) { int p = excl + local[i]; rptr[idx] = p; cur[idx] = p; }
  }
  if (t == 1023) rptr[N_NODES] = v;
}

// ---------------------------------------------------------------- scatter perm
__global__ void scatter_kernel(const int* __restrict__ dst, int* __restrict__ cur,
                               int* __restrict__ perm) {
  int e = blockIdx.x * blockDim.x + threadIdx.x;
  int d = dst[e];
  int pos = atomicAdd(&cur[d], 1);
  perm[pos] = e;
}

// ---------------------------------------------------------------- fused kernel
// 64 nodes/block. Edge phase: double-buffered 64-edge tiles, h = node[src]+eemb
// -> LDS bf16 -> MFMA GEMM (W1m) -> gelu -> LDS-atomic accumulate into A2 fp32.
// Node phase: A2/deg -> GEMM(W2m)+flag*b2m -> GEMM(W1u)+gelu (in 2 halves)
// -> GEMM(W2u)+b2u -> residual + LayerNorm -> out.
__global__ __launch_bounds__(256) void fused_kernel(
    const float* __restrict__ node, const float* __restrict__ eemb,
    const int* __restrict__ src, const int* __restrict__ dst,
    const int* __restrict__ rptr, const int* __restrict__ perm,
    const unsigned short* __restrict__ P1m, const float* __restrict__ b1m,
    const unsigned short* __restrict__ P2m, const float* __restrict__ b2m,
    const unsigned short* __restrict__ P1u, const float* __restrict__ b1u,
    const unsigned short* __restrict__ P2u, const float* __restrict__ b2u,
    const float* __restrict__ gamma, const float* __restrict__ beta,
    float* __restrict__ out) {
  __shared__ unsigned short tA[2][64 * 256];  // 2 x 32KB staging / later A-tiles
  __shared__ float A2[64 * 256];              // 64KB accum; later aggB | Hhalf; finally U
  __shared__ int dloc[2][64];
  __shared__ float fflag[64], fmu[64], frs[64];
  const int tid = threadIdx.x;
  const int n0 = blockIdx.x * 64;
  const int w = tid >> 6, l = tid & 63, lr = l & 15, lh = l >> 4;
  const int r = tid >> 2;           // staging row / node row (4 threads per row)
  const int cs = (tid & 3) * 64;    // staging column start

  // zero A2
#pragma unroll
  for (int i = 0; i < 16; ++i)
    ((float4*)A2)[i * 256 + tid] = make_float4(0.f, 0.f, 0.f, 0.f);

  int nhi = n0 + 64; if (nhi > N_NODES) nhi = N_NODES;
  const int e_begin = rptr[n0];
  const int e_end = rptr[nhi];
  const int nt = (e_end - e_begin + 63) >> 6;

  float bias_c[4];
#pragma unroll
  for (int c = 0; c < 4; ++c) bias_c[c] = b1m[w * 64 + c * 16 + lr];

  // ---- staging: tile t -> buffer b
  auto stage = [&](int t, int b) {
    const int ei = e_begin + t * 64 + r;
    const bool v = ei < e_end;
    const int e = v ? perm[ei] : 0;
    const int s = v ? src[e] : 0;
    if ((tid & 3) == 0) dloc[b][r] = v ? (dst[e] - n0) : -1;
    const float* ep = eemb + (size_t)e * 256 + cs;
    const float* np = node + (size_t)s * 256 + cs;
    char* tb = (char*)tA + b * 32768;
#pragma unroll
    for (int i = 0; i < 8; ++i) {
      float4 a = *(const float4*)(ep + i * 8);
      float4 bb = *(const float4*)(np + i * 8);
      float4 c = *(const float4*)(ep + i * 8 + 4);
      float4 d = *(const float4*)(np + i * 8 + 4);
      uint4 p;
      p.x = pk2(a.x + bb.x, a.y + bb.y);
      p.y = pk2(a.z + bb.z, a.w + bb.w);
      p.z = pk2(c.x + d.x, c.y + d.y);
      p.w = pk2(c.z + d.z, c.w + d.w);
      *(uint4*)(tb + SWZ(r, r * 512 + (cs + i * 8) * 2)) = p;
    }
  };

  // ---- edge GEMM + gelu + LDS scatter for buffer b
  auto do_tile = [&](int b) {
    const char* tb = (const char*)tA + b * 32768;
    f32x4 acc[4][4];
#pragma unroll
    for (int r4 = 0; r4 < 4; ++r4)
#pragma unroll
      for (int c = 0; c < 4; ++c) acc[r4][c] = f32x4{bias_c[c], bias_c[c], bias_c[c], bias_c[c]};
#pragma unroll
    for (int t = 0; t < 8; ++t) {
      short8 af[4], bfr[4];
#pragma unroll
      for (int r4 = 0; r4 < 4; ++r4) {
        int row = r4 * 16 + lr;
        af[r4] = *(const short8*)(tb + SWZ(row, row * 512 + t * 64 + lh * 16));
      }
#pragma unroll
      for (int c = 0; c < 4; ++c)
        bfr[c] = *(const short8*)(P1m + (size_t)(((w * 4 + c) * 8 + t) * 512 + l * 8));
#pragma unroll
      for (int r4 = 0; r4 < 4; ++r4)
#pragma unroll
        for (int c = 0; c < 4; ++c)
          acc[r4][c] = __builtin_amdgcn_mfma_f32_16x16x32_bf16(af[r4], bfr[c], acc[r4][c], 0, 0, 0);
    }
#pragma unroll
    for (int r4 = 0; r4 < 4; ++r4)
#pragma unroll
      for (int j = 0; j < 4; ++j) {
        int row = r4 * 16 + lh * 4 + j;
        int d = dloc[b][row];
        if (d >= 0) {
#pragma unroll
          for (int c = 0; c < 4; ++c) {
            int col = w * 64 + c * 16 + lr;
            atomicAdd((float*)((char*)A2 + A2OFF(d, col * 4)), gelu_exact(acc[r4][c][j]));
          }
        }
      }
  };

  if (nt > 0) stage(0, 0);
  for (int t = 0; t < nt; ++t) {
    __syncthreads();
    if (t + 1 < nt) stage(t + 1, (t + 1) & 1);
    do_tile(t & 1);
  }
  __syncthreads();

  // ---- pack A2/deg -> bf16 A-tile in tA[0]
  const int n = n0 + r;
  const bool valid = n < N_NODES;
  {
    int dg = valid ? (rptr[n + 1] - rptr[n]) : 0;
    float rec = 1.0f / fmaxf((float)dg, 1.0f);
    if ((tid & 3) == 0) fflag[r] = (dg > 0) ? 1.0f : 0.0f;
#pragma unroll
    for (int i = 0; i < 8; ++i) {
      float4 a = *(const float4*)((const char*)A2 + A2OFF(r, (cs + i * 8) * 4));
      float4 b = *(const float4*)((const char*)A2 + A2OFF(r, (cs + i * 8 + 4) * 4));
      uint4 p;
      p.x = pk2(a.x * rec, a.y * rec);
      p.y = pk2(a.z * rec, a.w * rec);
      p.z = pk2(b.x * rec, b.y * rec);
      p.w = pk2(b.z * rec, b.w * rec);
      *(uint4*)((char*)tA + SWZ(r, r * 512 + (cs + i * 8) * 2)) = p;
    }
  }
  __syncthreads();

  unsigned short* aggB = (unsigned short*)A2;          // 32KB (rows 64 x 256 bf16)
  unsigned short* Hs = (unsigned short*)A2 + 16384;    // 32KB (rows 64 x 256 bf16)
  float* tU = (float*)A2;                              // 64KB fp32 (final)

  // ---- GEMM1: agg = (A2/deg) @ W2m + flag*b2m -> aggB
  {
    f32x4 acc[4][4];
#pragma unroll
    for (int r4 = 0; r4 < 4; ++r4)
#pragma unroll
      for (int c = 0; c < 4; ++c) acc[r4][c] = f32x4{0.f, 0.f, 0.f, 0.f};
#pragma unroll
    for (int t = 0; t < 8; ++t) {
      short8 af[4], bfr[4];
#pragma unroll
      for (int r4 = 0; r4 < 4; ++r4) {
        int row = r4 * 16 + lr;
        af[r4] = *(const short8*)((const char*)tA + SWZ(row, row * 512 + t * 64 + lh * 16));
      }
#pragma unroll
      for (int c = 0; c < 4; ++c)
        bfr[c] = *(const short8*)(P2m + (size_t)(((w * 4 + c) * 8 + t) * 512 + l * 8));
#pragma unroll
      for (int r4 = 0; r4 < 4; ++r4)
#pragma unroll
        for (int c = 0; c < 4; ++c)
          acc[r4][c] = __builtin_amdgcn_mfma_f32_16x16x32_bf16(af[r4], bfr[c], acc[r4][c], 0, 0, 0);
    }
    __syncthreads();  // A2 fp32 fully consumed by pack; safe to overwrite as aggB
#pragma unroll
    for (int r4 = 0; r4 < 4; ++r4)
#pragma unroll
      for (int c = 0; c < 4; ++c) {
        int col = w * 64 + c * 16 + lr;
        float bm = b2m[col];
#pragma unroll
        for (int j = 0; j < 4; ++j) {
          int row = r4 * 16 + lh * 4 + j;
          float v = acc[r4][c][j] + fflag[row] * bm;
          *(unsigned short*)((char*)aggB + SWZ(row, row * 512 + col * 2)) = f2bf(v);
        }
      }
  }
  __syncthreads();

  // ---- GEMM2 (halves) + GEMM3: U = gelu(agg@W1u+b1u) @ W2u + b2u
  f32x4 acc3[4][4];
#pragma unroll
  for (int c = 0; c < 4; ++c) {
    float bb = b2u[w * 64 + c * 16 + lr];
#pragma unroll
    for (int r4 = 0; r4 < 4; ++r4) acc3[r4][c] = f32x4{bb, bb, bb, bb};
  }
#pragma unroll
  for (int half = 0; half < 2; ++half) {
    // GEMM2 half: Hh = gelu(agg @ W1u[:, half*256:+256] + b1u[half*256:+256])
    {
      f32x4 acc[4][4];
#pragma unroll
      for (int r4 = 0; r4 < 4; ++r4)
#pragma unroll
        for (int c = 0; c < 4; ++c) acc[r4][c] = f32x4{0.f, 0.f, 0.f, 0.f};
#pragma unroll
      for (int t = 0; t < 8; ++t) {
        short8 af[4], bfr[4];
#pragma unroll
        for (int r4 = 0; r4 < 4; ++r4) {
          int row = r4 * 16 + lr;
          af[r4] = *(const short8*)((const char*)aggB + SWZ(row, row * 512 + t * 64 + lh * 16));
        }
#pragma unroll
        for (int c = 0; c < 4; ++c)
          bfr[c] = *(const short8*)(P1u + (size_t)(((half * 16 + w * 4 + c) * 8 + t) * 512 + l * 8));
#pragma unroll
        for (int r4 = 0; r4 < 4; ++r4)
#pragma unroll
          for (int c = 0; c < 4; ++c)
            acc[r4][c] = __builtin_amdgcn_mfma_f32_16x16x32_bf16(af[r4], bfr[c], acc[r4][c], 0, 0, 0);
      }
#pragma unroll
      for (int r4 = 0; r4 < 4; ++r4)
#pragma unroll
        for (int c = 0; c < 4; ++c) {
          int col = w * 64 + c * 16 + lr;  // within half
          float b1 = b1u[half * 256 + col];
#pragma unroll
          for (int j = 0; j < 4; ++j) {
            int row = r4 * 16 + lh * 4 + j;
            float v = gelu_exact(acc[r4][c][j] + b1);
            *(unsigned short*)((char*)Hs + SWZ(row, row * 512 + col * 2)) = f2bf(v);
          }
        }
    }
    __syncthreads();
    // GEMM3 partial: acc3 += Hh @ W2u[half*256:+256, :]
    {
#pragma unroll
      for (int tt = 0; tt < 8; ++tt) {
        short8 af[4], bfr[4];
#pragma unroll
        for (int r4 = 0; r4 < 4; ++r4) {
          int row = r4 * 16 + lr;
          af[r4] = *(const short8*)((const char*)Hs + SWZ(row, row * 512 + tt * 64 + lh * 16));
        }
#pragma unroll
        for (int c = 0; c < 4; ++c)
          bfr[c] = *(const short8*)(P2u + (size_t)(((w * 4 + c) * 16 + half * 8 + tt) * 512 + l * 8));
#pragma unroll
        for (int r4 = 0; r4 < 4; ++r4)
#pragma unroll
          for (int c = 0; c < 4; ++c)
            acc3[r4][c] = __builtin_amdgcn_mfma_f32_16x16x32_bf16(af[r4], bfr[c], acc3[r4][c], 0, 0, 0);
      }
    }
    __syncthreads();
  }

  // ---- write U fp32 (aggB/Hs dead)
#pragma unroll
  for (int r4 = 0; r4 < 4; ++r4)
#pragma unroll
    for (int c = 0; c < 4; ++c) {
      int col = w * 64 + c * 16 + lr;
#pragma unroll
      for (int j = 0; j < 4; ++j) {
        int row = r4 * 16 + lh * 4 + j;
        *(float*)((char*)tU + SWZU(row * 1024 + col * 4)) = acc3[r4][c][j];
      }
    }
  __syncthreads();

  // ---- residual + LayerNorm stats
  {
    float sum = 0.f, sq = 0.f;
#pragma unroll
    for (int i = 0; i < 16; ++i) {
      int byte = SWZU(r * 1024 + (cs + i * 4) * 4);
      float4 v = *(float4*)((char*)tU + byte);
      if (valid) {
        const float4 nb = *(const float4*)(node + (size_t)n * 256 + cs + i * 4);
        v.x += nb.x; v.y += nb.y; v.z += nb.z; v.w += nb.w;
        *(float4*)((char*)tU + byte) = v;
      }
      sum += v.x + v.y + v.z + v.w;
      sq += v.x * v.x + v.y * v.y + v.z * v.z + v.w * v.w;
    }
    sum += __shfl_xor(sum, 1); sum += __shfl_xor(sum, 2);
    sq  += __shfl_xor(sq, 1);  sq  += __shfl_xor(sq, 2);
    if ((tid & 3) == 0) {
      float mu = sum * (1.0f / 256.0f);
      fmu[r] = mu;
      frs[r] = rsqrtf(fmaxf(sq * (1.0f / 256.0f) - mu * mu, 0.0f) + 1e-5f);
    }
  }
  __syncthreads();
#pragma unroll
  for (int i = 0; i < 16; ++i) {
    int f4 = i * 256 + tid;
    int row = f4 >> 6;
    int c4 = f4 & 63;
    int nn = n0 + row;
    if (nn < N_NODES) {
      float4 v = *(float4*)((char*)tU + SWZU(row * 1024 + c4 * 16));
      float mu = fmu[row], rs = frs[row];
      float4 g  = *(const float4*)(gamma + c4 * 4);
      float4 bt = *(const float4*)(beta + c4 * 4);
      float4 o;
      o.x = (v.x - mu) * rs * g.x + bt.x;
      o.y = (v.y - mu) * rs * g.y + bt.y;
      o.z = (v.z - mu) * rs * g.z + bt.z;
      o.w = (v.w - mu) * rs * g.w + bt.w;
      *(float4*)(out + (size_t)nn * 256 + c4 * 4) = o;
    }
  }
}

// ---------------------------------------------------------------- launch
extern "C" void kernel_launch(void* const* d_in, const int* in_sizes, int n_in,
                              void* d_out, int out_size, void* d_ws, size_t ws_size,
                              hipStream_t stream) {
  const float* node = (const float*)d_in[0];
  const int* eidx = (const int*)d_in[1];   // harness delivers integer inputs as int32
  const float* eemb = (const float*)d_in[2];
  const float* W1m = (const float*)d_in[3];
  const float* b1m = (const float*)d_in[4];
  const float* W2m = (const float*)d_in[5];
  const float* b2m = (const float*)d_in[6];
  const float* W1u = (const float*)d_in[7];
  const float* b1u = (const float*)d_in[8];
  const float* W2u = (const float*)d_in[9];
  const float* b2u = (const float*)d_in[10];
  const float* gamma = (const float*)d_in[11];
  const float* beta = (const float*)d_in[12];
  float* out = (float*)d_out;

  char* ws = (char*)d_ws;
  int* cnt  = (int*)ws;                                 // 80000 B
  int* rptr = (int*)(ws + 81920);                       // 80004 B
  int* cur  = (int*)(ws + 163840);                      // 80000 B
  int* perm = (int*)(ws + 245760);                      // 1280000 B
  unsigned short* P1m = (unsigned short*)(ws + 1525760);  // 131072 B
  unsigned short* P2m = (unsigned short*)(ws + 1656832);  // 131072 B
  unsigned short* P1u = (unsigned short*)(ws + 1787904);  // 262144 B
  unsigned short* P2u = (unsigned short*)(ws + 2050048);  // 262144 B
  const int* src = eidx;
  const int* dst = eidx + N_EDGES;

  zero_cnt_kernel<<<(N_NODES + 255) / 256, 256, 0, stream>>>(cnt);
  pack_kernel<<<393216 / 256, 256, 0, stream>>>(W1m, W2m, W1u, W2u, P1m, P2m, P1u, P2u);
  hist_kernel<<<N_EDGES / 256, 256, 0, stream>>>(dst, cnt);
  scan_kernel<<<1, 1024, 0, stream>>>(cnt, rptr, cur);
  scatter_kernel<<<N_EDGES / 256, 256, 0, stream>>>(dst, cur, perm);
  fused_kernel<<<(N_NODES + 63) / 64, 256, 0, stream>>>(
      node, eemb, src, dst, rptr, perm, P1m, b1m, P2m, b2m,
      P1u, b1u, P2u, b2u, gamma, beta, out);
}

// Round 4
// 387.170 us; speedup vs baseline: 2.6701x; 2.6701x over previous
//
#include <hip/hip_runtime.h>
#include <hip/hip_bf16.h>

#define N_NODES 20000
#define N_EDGES 320000

typedef __attribute__((ext_vector_type(8))) short short8;
typedef __attribute__((ext_vector_type(4))) float f32x4;

static __device__ __forceinline__ unsigned short f2bf(float f) {
  __hip_bfloat16 h = __float2bfloat16(f);
  union { __hip_bfloat16 h; unsigned short u; } cv; cv.h = h; return cv.u;
}

static __device__ __forceinline__ float bf2f(unsigned short u) {
  union { unsigned int u; float f; } cv; cv.u = ((unsigned int)u) << 16; return cv.f;
}

static __device__ __forceinline__ unsigned int pk2(float a, float b) {
  return (unsigned int)f2bf(a) | ((unsigned int)f2bf(b) << 16);
}

static __device__ __forceinline__ float gelu_exact(float v) {
  return 0.5f * v * (1.0f + erff(v * 0.70710678118654752f));
}

// XOR swizzle for bf16 tiles with 512B/1024B row stride (16B granule spread)
#define SWZ(row, byteoff) ((byteoff) ^ (((row) & 7) << 4))
// fp32 U tile swizzle keyed off address bits
#define SWZU(b) ((b) ^ ((((b) >> 8) & 7) << 4))

// ---------------------------------------------------------------- zero S + cnt
__global__ void zero_kernel(float4* __restrict__ S4, int4* __restrict__ cnt4) {
  int idx = blockIdx.x * blockDim.x + threadIdx.x;
  S4[idx] = make_float4(0.f, 0.f, 0.f, 0.f);
  if (idx < N_NODES / 4) cnt4[idx] = make_int4(0, 0, 0, 0);
}

// ---------------------------------------------------------------- weight pack
// Pack W[K][Nc] (row-major f32) into bf16 MFMA-B-fragment order:
// P[(cf*(K/32)+t)*512 + l*8 + i] = W[t*32 + (l>>4)*8 + i][cf*16 + (l&15)]
__global__ void pack_kernel(const float* __restrict__ W1m, const float* __restrict__ W2m,
                            const float* __restrict__ W1u, const float* __restrict__ W2u,
                            unsigned short* __restrict__ P1m, unsigned short* __restrict__ P2m,
                            unsigned short* __restrict__ P1u, unsigned short* __restrict__ P2u) {
  int idx = blockIdx.x * blockDim.x + threadIdx.x;
  const float* W; unsigned short* P; int K, Nc, local;
  if (idx < 65536)        { W = W1m; P = P1m; K = 256; Nc = 256; local = idx; }
  else if (idx < 131072)  { W = W2m; P = P2m; K = 256; Nc = 256; local = idx - 65536; }
  else if (idx < 262144)  { W = W1u; P = P1u; K = 256; Nc = 512; local = idx - 131072; }
  else                    { W = W2u; P = P2u; K = 512; Nc = 256; local = idx - 262144; }
  int frag = local >> 9, wi = local & 511;
  int l = wi >> 3, i = wi & 7;
  int kf = K >> 5;
  int cf = frag / kf, t = frag % kf;
  int k = t * 32 + (l >> 4) * 8 + i;
  int n = cf * 16 + (l & 15);
  P[local] = f2bf(W[(size_t)k * Nc + n]);
}

// ---------------------------------------------------------------- histogram
__global__ void hist_kernel(const int* __restrict__ dst, int* __restrict__ cnt) {
  int e = blockIdx.x * blockDim.x + threadIdx.x;
  atomicAdd(&cnt[dst[e]], 1);
}

// ---------------------------------------------------------------- prefix scan (1 block, 1024 thr)
__global__ __launch_bounds__(1024) void scan_kernel(const int* __restrict__ cnt,
                                                    int* __restrict__ rptr,
                                                    int* __restrict__ cur) {
  __shared__ int sums[1024];
  const int t = threadIdx.x;
  const int base = t * 20;
  int local[20];
  int s = 0;
#pragma unroll
  for (int i = 0; i < 20; ++i) {
    int idx = base + i;
    int v = (idx < N_NODES) ? cnt[idx] : 0;
    local[i] = s;
    s += v;
  }
  int v = s;
  sums[t] = v;
  for (int off = 1; off < 1024; off <<= 1) {
    __syncthreads();
    int o = (t >= off) ? sums[t - off] : 0;
    __syncthreads();
    v += o;
    sums[t] = v;
  }
  int excl = v - s;
#pragma unroll
  for (int i = 0; i < 20; ++i) {
    int idx = base + i;
    if (idx < N_NODES) { int p = excl + local[i]; rptr[idx] = p; cur[idx] = p; }
  }
  if (t == 1023) rptr[N_NODES] = v;
}

// ---------------------------------------------------------------- scatter perm
__global__ void scatter_kernel(const int* __restrict__ dst, int* __restrict__ cur,
                               int* __restrict__ perm) {
  int e = blockIdx.x * blockDim.x + threadIdx.x;
  int d = dst[e];
  int pos = atomicAdd(&cur[d], 1);
  perm[pos] = e;
}

// ---------------------------------------------------------------- edge kernel
// 64 dst-sorted edges/block, 4 waves, LDS 33KB -> 4 blocks/CU.
// h = node[src]+eemb -> LDS bf16 -> MFMA(W1m)+b1m -> gelu -> write back to LDS
// -> per-column segmented reduction over sorted rows -> ~5 coalesced
// atomicAdd row-flushes per tile (instead of 64 scattered ones).
__global__ __launch_bounds__(256) void edge_kernel(
    const float* __restrict__ node, const float* __restrict__ eemb,
    const int* __restrict__ src, const int* __restrict__ dst,
    const int* __restrict__ perm,
    const unsigned short* __restrict__ P1m, const float* __restrict__ b1m,
    float* __restrict__ S) {
  __shared__ unsigned short tA[64 * 256];
  __shared__ int dstS[64];
  const int tid = threadIdx.x;
  const int e0 = blockIdx.x * 64;
  {
    const int r = tid >> 2;
    const int cs = (tid & 3) * 64;
    const int e = perm[e0 + r];
    const int se = src[e];
    if ((tid & 3) == 0) dstS[r] = dst[e];
    const float* ep = eemb + (size_t)e * 256 + cs;
    const float* np = node + (size_t)se * 256 + cs;
#pragma unroll
    for (int i = 0; i < 8; ++i) {
      float4 a = *(const float4*)(ep + i * 8);
      float4 b = *(const float4*)(np + i * 8);
      float4 c = *(const float4*)(ep + i * 8 + 4);
      float4 d = *(const float4*)(np + i * 8 + 4);
      uint4 p;
      p.x = pk2(a.x + b.x, a.y + b.y);
      p.y = pk2(a.z + b.z, a.w + b.w);
      p.z = pk2(c.x + d.x, c.y + d.y);
      p.w = pk2(c.z + d.z, c.w + d.w);
      *(uint4*)((char*)tA + SWZ(r, r * 512 + (cs + i * 8) * 2)) = p;
    }
  }
  __syncthreads();

  const int w = tid >> 6, l = tid & 63;
  const int lr = l & 15, lh = l >> 4;
  f32x4 acc[4][4];
#pragma unroll
  for (int c = 0; c < 4; ++c) {
    float bb = b1m[w * 64 + c * 16 + lr];
#pragma unroll
    for (int r4 = 0; r4 < 4; ++r4) acc[r4][c] = f32x4{bb, bb, bb, bb};
  }
#pragma unroll
  for (int t = 0; t < 8; ++t) {
    short8 af[4], bfr[4];
#pragma unroll
    for (int r4 = 0; r4 < 4; ++r4) {
      int row = r4 * 16 + lr;
      af[r4] = *(const short8*)((const char*)tA + SWZ(row, row * 512 + t * 64 + lh * 16));
    }
#pragma unroll
    for (int c = 0; c < 4; ++c)
      bfr[c] = *(const short8*)(P1m + (size_t)(((w * 4 + c) * 8 + t) * 512 + l * 8));
#pragma unroll
    for (int r4 = 0; r4 < 4; ++r4)
#pragma unroll
      for (int c = 0; c < 4; ++c)
        acc[r4][c] = __builtin_amdgcn_mfma_f32_16x16x32_bf16(af[r4], bfr[c], acc[r4][c], 0, 0, 0);
  }
  __syncthreads();  // all reads of tA done; safe to overwrite

  // gelu -> write messages back into tA (bf16)
#pragma unroll
  for (int r4 = 0; r4 < 4; ++r4)
#pragma unroll
    for (int c = 0; c < 4; ++c) {
      int col = w * 64 + c * 16 + lr;
#pragma unroll
      for (int j = 0; j < 4; ++j) {
        int row = r4 * 16 + lh * 4 + j;
        *(unsigned short*)((char*)tA + SWZ(row, row * 512 + col * 2)) =
            f2bf(gelu_exact(acc[r4][c][j]));
      }
    }
  __syncthreads();

  // segmented column reduction over sorted rows; one atomic row-flush per dst
  {
    const int col = tid;
    float run = 0.f;
    int cur = dstS[0];
#pragma unroll 8
    for (int row = 0; row < 64; ++row) {
      int d = dstS[row];
      float v = bf2f(*(const unsigned short*)((const char*)tA + SWZ(row, row * 512 + col * 2)));
      if (d != cur) {
        atomicAdd(&S[(size_t)cur * 256 + col], run);
        run = 0.f;
        cur = d;
      }
      run += v;
    }
    atomicAdd(&S[(size_t)cur * 256 + col], run);
  }
}

// ---------------------------------------------------------------- node kernel
// 64 nodes/block: A2 = S/max(deg,1); agg = A2@W2m + (deg>0)b2m;
// H = gelu(agg@W1u + b1u); U = H@W2u + b2u; out = LN(node + U)*gamma + beta.
__global__ __launch_bounds__(256) void node_kernel(
    const float* __restrict__ node, const float* __restrict__ S, const int* __restrict__ rptr,
    const unsigned short* __restrict__ P2m, const float* __restrict__ b2m,
    const unsigned short* __restrict__ P1u, const float* __restrict__ b1u,
    const unsigned short* __restrict__ P2u, const float* __restrict__ b2u,
    const float* __restrict__ gamma, const float* __restrict__ beta,
    float* __restrict__ out) {
  __shared__ unsigned short tAB[2][64 * 256];  // 64 KB: [0]=A2, [1]=agg; reused as fp32 U
  __shared__ unsigned short tH[64 * 512];      // 64 KB
  __shared__ float fmu[64], frs[64], fflag[64];
  float* tU = (float*)tAB;
  const int tid = threadIdx.x;
  const int n0 = blockIdx.x * 64;
  const int r = tid >> 2;
  const int cs = (tid & 3) * 64;
  const int n = n0 + r;
  const bool valid = n < N_NODES;
  {
    int dgi = valid ? (rptr[n + 1] - rptr[n]) : 0;
    float dg = (float)dgi;
    float rec = 1.0f / fmaxf(dg, 1.0f);
    if ((tid & 3) == 0) fflag[r] = (dgi > 0) ? 1.0f : 0.0f;
    const float4* sp = (const float4*)(S + (size_t)n * 256 + cs);
#pragma unroll
    for (int i = 0; i < 8; ++i) {
      float4 a = valid ? sp[2 * i]     : make_float4(0.f, 0.f, 0.f, 0.f);
      float4 b = valid ? sp[2 * i + 1] : make_float4(0.f, 0.f, 0.f, 0.f);
      uint4 p;
      p.x = pk2(a.x * rec, a.y * rec);
      p.y = pk2(a.z * rec, a.w * rec);
      p.z = pk2(b.x * rec, b.y * rec);
      p.w = pk2(b.z * rec, b.w * rec);
      *(uint4*)((char*)tAB[0] + SWZ(r, r * 512 + (cs + i * 8) * 2)) = p;
    }
  }
  __syncthreads();
  const int w = tid >> 6, l = tid & 63, lr = l & 15, lh = l >> 4;

  // ---- GEMM1: agg = A2 @ W2m + flag*b2m -> tAB[1] (bf16)
  {
    f32x4 acc[4][4];
#pragma unroll
    for (int r4 = 0; r4 < 4; ++r4)
#pragma unroll
      for (int c = 0; c < 4; ++c) acc[r4][c] = f32x4{0.f, 0.f, 0.f, 0.f};
#pragma unroll
    for (int t = 0; t < 8; ++t) {
      short8 af[4], bfr[4];
#pragma unroll
      for (int r4 = 0; r4 < 4; ++r4) {
        int row = r4 * 16 + lr;
        af[r4] = *(const short8*)((const char*)tAB[0] + SWZ(row, row * 512 + t * 64 + lh * 16));
      }
#pragma unroll
      for (int c = 0; c < 4; ++c)
        bfr[c] = *(const short8*)(P2m + (size_t)(((w * 4 + c) * 8 + t) * 512 + l * 8));
#pragma unroll
      for (int r4 = 0; r4 < 4; ++r4)
#pragma unroll
        for (int c = 0; c < 4; ++c)
          acc[r4][c] = __builtin_amdgcn_mfma_f32_16x16x32_bf16(af[r4], bfr[c], acc[r4][c], 0, 0, 0);
    }
#pragma unroll
    for (int r4 = 0; r4 < 4; ++r4)
#pragma unroll
      for (int c = 0; c < 4; ++c) {
        int col = w * 64 + c * 16 + lr;
        float bm = b2m[col];
#pragma unroll
        for (int j = 0; j < 4; ++j) {
          int row = r4 * 16 + lh * 4 + j;
          float v = acc[r4][c][j] + fflag[row] * bm;
          *(unsigned short*)((char*)tAB[1] + SWZ(row, row * 512 + col * 2)) = f2bf(v);
        }
      }
  }
  __syncthreads();

  // ---- GEMM2: H = gelu(agg @ W1u + b1u) -> tH (64x512 bf16)
  {
    f32x4 acc[4][8];
#pragma unroll
    for (int r4 = 0; r4 < 4; ++r4)
#pragma unroll
      for (int c = 0; c < 8; ++c) acc[r4][c] = f32x4{0.f, 0.f, 0.f, 0.f};
#pragma unroll
    for (int t = 0; t < 8; ++t) {
      short8 af[4], bfr[8];
#pragma unroll
      for (int r4 = 0; r4 < 4; ++r4) {
        int row = r4 * 16 + lr;
        af[r4] = *(const short8*)((const char*)tAB[1] + SWZ(row, row * 512 + t * 64 + lh * 16));
      }
#pragma unroll
      for (int c = 0; c < 8; ++c)
        bfr[c] = *(const short8*)(P1u + (size_t)(((w * 8 + c) * 8 + t) * 512 + l * 8));
#pragma unroll
      for (int r4 = 0; r4 < 4; ++r4)
#pragma unroll
        for (int c = 0; c < 8; ++c)
          acc[r4][c] = __builtin_amdgcn_mfma_f32_16x16x32_bf16(af[r4], bfr[c], acc[r4][c], 0, 0, 0);
    }
#pragma unroll
    for (int r4 = 0; r4 < 4; ++r4)
#pragma unroll
      for (int c = 0; c < 8; ++c) {
        int col = w * 128 + c * 16 + lr;
        float b1 = b1u[col];
#pragma unroll
        for (int j = 0; j < 4; ++j) {
          int row = r4 * 16 + lh * 4 + j;
          float v = gelu_exact(acc[r4][c][j] + b1);
          *(unsigned short*)((char*)tH + SWZ(row, row * 1024 + col * 2)) = f2bf(v);
        }
      }
  }
  __syncthreads();

  // ---- GEMM3: U = H @ W2u + b2u -> tU (fp32, SWZU)  [tAB dead -> reuse as tU]
  {
    f32x4 acc[4][4];
#pragma unroll
    for (int r4 = 0; r4 < 4; ++r4)
#pragma unroll
      for (int c = 0; c < 4; ++c) acc[r4][c] = f32x4{0.f, 0.f, 0.f, 0.f};
#pragma unroll
    for (int t = 0; t < 16; ++t) {
      short8 af[4], bfr[4];
#pragma unroll
      for (int r4 = 0; r4 < 4; ++r4) {
        int row = r4 * 16 + lr;
        af[r4] = *(const short8*)((const char*)tH + SWZ(row, row * 1024 + t * 64 + lh * 16));
      }
#pragma unroll
      for (int c = 0; c < 4; ++c)
        bfr[c] = *(const short8*)(P2u + (size_t)(((w * 4 + c) * 16 + t) * 512 + l * 8));
#pragma unroll
      for (int r4 = 0; r4 < 4; ++r4)
#pragma unroll
        for (int c = 0; c < 4; ++c)
          acc[r4][c] = __builtin_amdgcn_mfma_f32_16x16x32_bf16(af[r4], bfr[c], acc[r4][c], 0, 0, 0);
    }
#pragma unroll
    for (int r4 = 0; r4 < 4; ++r4)
#pragma unroll
      for (int c = 0; c < 4; ++c) {
        int col = w * 64 + c * 16 + lr;
        float b2 = b2u[col];
#pragma unroll
        for (int j = 0; j < 4; ++j) {
          int row = r4 * 16 + lh * 4 + j;
          *(float*)((char*)tU + SWZU(row * 1024 + col * 4)) = acc[r4][c][j] + b2;
        }
      }
  }
  __syncthreads();

  // ---- residual + LayerNorm stats
  {
    float sum = 0.f, sq = 0.f;
#pragma unroll
    for (int i = 0; i < 16; ++i) {
      int byte = SWZU(r * 1024 + (cs + i * 4) * 4);
      float4 v = *(float4*)((char*)tU + byte);
      if (valid) {
        const float4 nb = *(const float4*)(node + (size_t)n * 256 + cs + i * 4);
        v.x += nb.x; v.y += nb.y; v.z += nb.z; v.w += nb.w;
        *(float4*)((char*)tU + byte) = v;
      }
      sum += v.x + v.y + v.z + v.w;
      sq += v.x * v.x + v.y * v.y + v.z * v.z + v.w * v.w;
    }
    sum += __shfl_xor(sum, 1); sum += __shfl_xor(sum, 2);
    sq  += __shfl_xor(sq, 1);  sq  += __shfl_xor(sq, 2);
    if ((tid & 3) == 0) {
      float mu = sum * (1.0f / 256.0f);
      fmu[r] = mu;
      frs[r] = rsqrtf(fmaxf(sq * (1.0f / 256.0f) - mu * mu, 0.0f) + 1e-5f);
    }
  }
  __syncthreads();
#pragma unroll
  for (int i = 0; i < 16; ++i) {
    int f4 = i * 256 + tid;
    int row = f4 >> 6;
    int c4 = f4 & 63;
    int nn = n0 + row;
    if (nn < N_NODES) {
      float4 v = *(float4*)((char*)tU + SWZU(row * 1024 + c4 * 16));
      float mu = fmu[row], rs = frs[row];
      float4 g  = *(const float4*)(gamma + c4 * 4);
      float4 bt = *(const float4*)(beta + c4 * 4);
      float4 o;
      o.x = (v.x - mu) * rs * g.x + bt.x;
      o.y = (v.y - mu) * rs * g.y + bt.y;
      o.z = (v.z - mu) * rs * g.z + bt.z;
      o.w = (v.w - mu) * rs * g.w + bt.w;
      *(float4*)(out + (size_t)nn * 256 + c4 * 4) = o;
    }
  }
}

// ---------------------------------------------------------------- launch
extern "C" void kernel_launch(void* const* d_in, const int* in_sizes, int n_in,
                              void* d_out, int out_size, void* d_ws, size_t ws_size,
                              hipStream_t stream) {
  const float* node = (const float*)d_in[0];
  const int* eidx = (const int*)d_in[1];   // harness delivers integer inputs as int32
  const float* eemb = (const float*)d_in[2];
  const float* W1m = (const float*)d_in[3];
  const float* b1m = (const float*)d_in[4];
  const float* W2m = (const float*)d_in[5];
  const float* b2m = (const float*)d_in[6];
  const float* W1u = (const float*)d_in[7];
  const float* b1u = (const float*)d_in[8];
  const float* W2u = (const float*)d_in[9];
  const float* b2u = (const float*)d_in[10];
  const float* gamma = (const float*)d_in[11];
  const float* beta = (const float*)d_in[12];
  float* out = (float*)d_out;  // doubles as the scatter accumulator S [N,256] f32

  char* ws = (char*)d_ws;
  int* cnt  = (int*)ws;                                   // 80000 B
  int* rptr = (int*)(ws + 81920);                         // 80004 B
  int* cur  = (int*)(ws + 163840);                        // 80000 B
  int* perm = (int*)(ws + 245760);                        // 1280000 B
  unsigned short* P1m = (unsigned short*)(ws + 1525760);  // 131072 B
  unsigned short* P2m = (unsigned short*)(ws + 1656832);  // 131072 B
  unsigned short* P1u = (unsigned short*)(ws + 1787904);  // 262144 B
  unsigned short* P2u = (unsigned short*)(ws + 2050048);  // 262144 B
  const int* src = eidx;
  const int* dst = eidx + N_EDGES;

  zero_kernel<<<N_NODES * 64 / 256, 256, 0, stream>>>((float4*)out, (int4*)cnt);
  pack_kernel<<<393216 / 256, 256, 0, stream>>>(W1m, W2m, W1u, W2u, P1m, P2m, P1u, P2u);
  hist_kernel<<<N_EDGES / 256, 256, 0, stream>>>(dst, cnt);
  scan_kernel<<<1, 1024, 0, stream>>>(cnt, rptr, cur);
  scatter_kernel<<<N_EDGES / 256, 256, 0, stream>>>(dst, cur, perm);
  edge_kernel<<<N_EDGES / 64, 256, 0, stream>>>(node, eemb, src, dst, perm, P1m, b1m, out);
  node_kernel<<<(N_NODES + 63) / 64, 256, 0, stream>>>(node, out, rptr, P2m, b2m,
                                                       P1u, b1u, P2u, b2u, gamma, beta, out);
}